// Round 3
// baseline (546.131 us; speedup 1.0000x reference)
//
#include <hip/hip_runtime.h>
#include <float.h>
#include <stdint.h>

// IQE quasimetric:  per row, measure of union of [x_j, y_j] over j with x_j < y_j.
// Identity: a = sort(valid ? x : FLT_MAX), b = sort(valid ? y : FLT_MAX)
//           result = sum_i max(0, b_i - max(a_i, b_{i-1})),  b_{-1} = -inf.
//
// Layout: 4 lanes per row, 32 elements per lane; all cross-lane ops quad_perm DPP.
// This round: global_load_lds staging (contiguous 1-KB requests) + hand-pipelined
// single-buffer double-use: wait prev glds -> ds_read to regs -> lgkmcnt(0) ->
// issue next chunk's glds into same buffer -> sort (hides HBM latency under 4.5k
// cycles of VALU). 512 persistent blocks x 16 chunks; 64 KB LDS -> 2 blocks/CU.

constexpr int D = 128;
#define INF __builtin_huge_valf()

__device__ inline float med3(float a, float b, float c) {
    return __builtin_amdgcn_fmed3f(a, b, c);
}

// DPP quad_perm move (VALU pipe). CTRL 0x00-0xFF = quad_perm.
template<int CTRL>
__device__ inline float dppmov(float v) {
    int i = __builtin_amdgcn_mov_dpp(__float_as_int(v), CTRL, 0xF, 0xF, true);
    return __int_as_float(i);
}
constexpr int QP_XOR1 = 0xB1; // quad_perm [1,0,3,2]  : lane ^= 1
constexpr int QP_XOR2 = 0x4E; // quad_perm [2,3,0,1]  : lane ^= 2
constexpr int QP_SHR1 = 0x90; // quad_perm [0,0,1,2]  : lane g <- g-1 (g=0 self)

// compile-time-direction in-lane CE
__device__ inline void cea(float& u, float& v) { float lo = fminf(u, v), hi = fmaxf(u, v); u = lo; v = hi; }
__device__ inline void ced(float& u, float& v) { float lo = fminf(u, v), hi = fmaxf(u, v); u = hi; v = lo; }
// per-lane-direction in-lane CE: s = +-INF selector; lo slot u gets med3(u,v,s)
__device__ inline void cek(float& u, float& v, float s) {
    float lo = med3(u, v, s), hi = med3(u, v, -s); u = lo; v = hi;
}

// in-lane substep, compile-time stage K (direction from r&K) and pair distance J
template<int K, int J>
__device__ inline void sub_ct(float (&v)[32]) {
    #pragma unroll
    for (int r = 0; r < 32; r++)
        if (!(r & J)) { if (!(r & K)) cea(v[r], v[r + J]); else ced(v[r], v[r + J]); }
}
// in-lane substep, runtime direction selector s (stage bit lives in lane id)
template<int J>
__device__ inline void sub_rt(float (&v)[32], float s) {
    #pragma unroll
    for (int r = 0; r < 32; r++)
        if (!(r & J)) cek(v[r], v[r + J], s);
}
// cross-lane substep via quad_perm: partner = lane^mask; each lane keeps min/max per sel
template<int CTRL>
__device__ inline void cross(float (&v)[32], float sel) {
    #pragma unroll
    for (int r = 0; r < 32; r++) {
        float t = dppmov<CTRL>(v[r]);
        v[r] = med3(v[r], t, sel);
    }
}

// full bitonic-128 over e = 32*g + r, arrays a and b in lockstep
__device__ inline void sort128(float (&a)[32], float (&b)[32],
                               float M1, float M2, float C1) {
    sub_ct<2, 1>(a);  sub_ct<2, 1>(b);
    sub_ct<4, 2>(a);  sub_ct<4, 2>(b);
    sub_ct<4, 1>(a);  sub_ct<4, 1>(b);
    sub_ct<8, 4>(a);  sub_ct<8, 4>(b);
    sub_ct<8, 2>(a);  sub_ct<8, 2>(b);
    sub_ct<8, 1>(a);  sub_ct<8, 1>(b);
    sub_ct<16, 8>(a); sub_ct<16, 8>(b);
    sub_ct<16, 4>(a); sub_ct<16, 4>(b);
    sub_ct<16, 2>(a); sub_ct<16, 2>(b);
    sub_ct<16, 1>(a); sub_ct<16, 1>(b);
    sub_rt<16>(a, M1); sub_rt<16>(b, M1);
    sub_rt<8>(a, M1);  sub_rt<8>(b, M1);
    sub_rt<4>(a, M1);  sub_rt<4>(b, M1);
    sub_rt<2>(a, M1);  sub_rt<2>(b, M1);
    sub_rt<1>(a, M1);  sub_rt<1>(b, M1);
    cross<QP_XOR1>(a, C1); cross<QP_XOR1>(b, C1);
    sub_rt<16>(a, M2); sub_rt<16>(b, M2);
    sub_rt<8>(a, M2);  sub_rt<8>(b, M2);
    sub_rt<4>(a, M2);  sub_rt<4>(b, M2);
    sub_rt<2>(a, M2);  sub_rt<2>(b, M2);
    sub_rt<1>(a, M2);  sub_rt<1>(b, M2);
    cross<QP_XOR2>(a, M2); cross<QP_XOR2>(b, M2);
    cross<QP_XOR1>(a, M1); cross<QP_XOR1>(b, M1);
    sub_ct<128, 16>(a); sub_ct<128, 16>(b);
    sub_ct<128, 8>(a);  sub_ct<128, 8>(b);
    sub_ct<128, 4>(a);  sub_ct<128, 4>(b);
    sub_ct<128, 2>(a);  sub_ct<128, 2>(b);
    sub_ct<128, 1>(a);  sub_ct<128, 1>(b);
}

__device__ inline void glds16(const float* g, float* l) {
    __builtin_amdgcn_global_load_lds(
        (const __attribute__((address_space(1))) void*)g,
        (__attribute__((address_space(3))) void*)l, 16, 0, 0);
}

__global__ __launch_bounds__(256) void iqe_union_kernel(
    const float* __restrict__ x, const float* __restrict__ y,
    float* __restrict__ out, int B, int nch)
{
    __shared__ float lds[16384];                 // 4 waves x 16 KB private buffer
    const int tid  = threadIdx.x;
    const int lane = tid & 63;
    const int wid  = tid >> 6;
    const int g    = tid & 3;                    // lane within 4-lane row group
    const int lrow = (tid >> 2) & 15;            // row slot within wave (0..15)
    float* wbuf = &lds[wid * 4096];              // x at +0 (2048 f), y at +2048

    // per-lane bit signs and +-INF selectors
    const float S1 = (g & 1) ? 1.f : -1.f;
    const float S2 = (g & 2) ? 1.f : -1.f;
    const float M1 = S1 * INF;
    const float M2 = S2 * INF;
    const float C1 = -S1 * S2 * INF;

    const int blockRow0 = blockIdx.x * nch * 64; // contiguous region per block

    // stage chunk c's 16 rows for this wave: 8+8 glds, each a contiguous 1 KB
    // (64 lanes x 16 B linear). LDS dest = wave-uniform base + lane*16 (linear).
    auto stage = [&](int c) {
        const int r0 = blockRow0 + c * 64 + wid * 16;
        if (r0 >= B) return;
        const float* sx = x + (size_t)r0 * D + lane * 4;
        const float* sy = y + (size_t)r0 * D + lane * 4;
        #pragma unroll
        for (int j = 0; j < 8; j++) glds16(sx + j * 256, wbuf + j * 256);
        #pragma unroll
        for (int j = 0; j < 8; j++) glds16(sy + j * 256, wbuf + 2048 + j * 256);
    };

    stage(0);

    for (int c = 0; c < nch; c++) {
        const int row = blockRow0 + c * 64 + wid * 16 + lrow;

        // current chunk's glds complete
        asm volatile("s_waitcnt vmcnt(0)" ::: "memory");
        __builtin_amdgcn_sched_barrier(0);

        // LDS -> regs: quad (lrow,g) reads its row; chunk rotation (t+lrow)&7
        // spreads banks uniformly (free: sort is input-permutation-invariant)
        float a[32], b[32];
        #pragma unroll
        for (int t = 0; t < 8; t++) {
            const int rd = (t + lrow) & 7;
            *reinterpret_cast<float4*>(&a[4 * t]) =
                *reinterpret_cast<const float4*>(wbuf + lrow * 128 + rd * 16 + g * 4);
            *reinterpret_cast<float4*>(&b[4 * t]) =
                *reinterpret_cast<const float4*>(wbuf + 2048 + lrow * 128 + rd * 16 + g * 4);
        }

        // reads retired -> safe to overwrite buffer with next chunk's glds
        asm volatile("s_waitcnt lgkmcnt(0)" ::: "memory");
        __builtin_amdgcn_sched_barrier(0);
        if (c + 1 < nch) stage(c + 1);           // flies under the sort below

        // mask invalid intervals (x >= y) to +INF in both arrays
        #pragma unroll
        for (int r = 0; r < 32; r++) {
            const bool v = a[r] < b[r];
            a[r] = v ? a[r] : FLT_MAX;
            b[r] = v ? b[r] : FLT_MAX;
        }

        sort128(a, b, M1, M2, C1);

        // epilogue: sum max(0, b_e - max(a_e, b_{e-1}))
        float prev = dppmov<QP_SHR1>(b[31]);
        if (g == 0) prev = -FLT_MAX;
        float acc = 0.f;
        #pragma unroll
        for (int r = 0; r < 32; r++) {
            acc += fmaxf(0.f, b[r] - fmaxf(a[r], prev));
            prev = b[r];
        }
        acc += dppmov<QP_XOR1>(acc);
        acc += dppmov<QP_XOR2>(acc);
        if (g == 0 && row < B) out[row] = acc;
    }
}

extern "C" void kernel_launch(void* const* d_in, const int* in_sizes, int n_in,
                              void* d_out, int out_size, void* d_ws, size_t ws_size,
                              hipStream_t stream) {
    const float* x = (const float*)d_in[0];
    const float* y = (const float*)d_in[1];
    float* out = (float*)d_out;
    const int B = in_sizes[0] / D;                    // 524288
    const int blocks = 512;                           // 2 blocks/CU (64 KB LDS each)
    const int nch = (B + blocks * 64 - 1) / (blocks * 64);  // 16 chunks of 64 rows
    iqe_union_kernel<<<blocks, 256, 0, stream>>>(x, y, out, B, nch);
}

// Round 4
// 524.274 us; speedup vs baseline: 1.0417x; 1.0417x over previous
//
#include <hip/hip_runtime.h>
#include <float.h>

// IQE quasimetric:  per row, measure of union of [x_j, y_j] over j with x_j < y_j.
// Identity: a = sort(valid ? x : FLT_MAX), b = sort(valid ? y : FLT_MAX)
//           result = sum_i max(0, b_i - max(a_i, b_{i-1})),  b_{-1} = -inf.
//
// Layout: 4 lanes per row, 32 elements per lane (e = 32*g + r), 16 rows per wave.
// Sorting network: REFLECTION bitonic — every merge stage m is
//   reflect-compare (i, m-1-i)  then all-ASCENDING half-cleaners (xor distances).
// => all in-lane CEs are plain v_min/v_max (2-src, full-rate); only the 3
//    cross-lane substeps (m=64 reflect, m=128 reflect, m=128 dist-32 cleaner)
//    need med3 with per-lane +-INF selectors. In-lane reflections are free
//    (compile-time register index reversal). m<=16 stages factor into two
//    independent 16-reg halves -> loads ordered lo/hi so the hi-load latency
//    hides under the lo-half sort (natural vmcnt(8), zero extra registers).

constexpr int D = 128;
#define INF __builtin_huge_valf()

__device__ inline float med3(float a, float b, float c) {
    return __builtin_amdgcn_fmed3f(a, b, c);
}

// DPP quad_perm move (VALU pipe). CTRL 0x00-0xFF = quad_perm.
template<int CTRL>
__device__ inline float dppmov(float v) {
    int i = __builtin_amdgcn_mov_dpp(__float_as_int(v), CTRL, 0xF, 0xF, true);
    return __int_as_float(i);
}
constexpr int QP_XOR1 = 0xB1; // quad_perm [1,0,3,2] : lane ^= 1
constexpr int QP_XOR3 = 0x1B; // quad_perm [3,2,1,0] : lane ^= 3 (reflection)
constexpr int QP_SHR1 = 0x90; // quad_perm [0,0,1,2] : lane g <- g-1 (g=0 self)

// ascending compare-exchange (2-src min/max only)
__device__ inline void cea(float& u, float& v) {
    float lo = fminf(u, v), hi = fmaxf(u, v); u = lo; v = hi;
}

// uniform-ascending xor substep, distance J, over regs [R0, R0+N)
template<int R0, int N, int J>
__device__ inline void clean(float (&v)[32]) {
    #pragma unroll
    for (int i = 0; i < N; i++)
        if (!(i & J)) cea(v[R0 + i], v[R0 + i + J]);
}
// in-lane reflection substep, block size M, over regs [R0, R0+N)
template<int R0, int N, int M>
__device__ inline void reflect(float (&v)[32]) {
    #pragma unroll
    for (int b = 0; b < N; b += M)
        #pragma unroll
        for (int i = 0; i < M / 2; i++)
            cea(v[R0 + b + i], v[R0 + b + M - 1 - i]);
}

// sort 16 regs [R0, R0+16) ascending (merges m=2..16, all compile-time)
template<int R0>
__device__ inline void sort16(float (&v)[32]) {
    reflect<R0, 16, 2>(v);
    reflect<R0, 16, 4>(v);  clean<R0, 16, 1>(v);
    reflect<R0, 16, 8>(v);  clean<R0, 16, 2>(v); clean<R0, 16, 1>(v);
    reflect<R0, 16, 16>(v); clean<R0, 16, 4>(v); clean<R0, 16, 2>(v); clean<R0, 16, 1>(v);
}

// cross-lane reflected gather: t[r] = partner-lane's v[31-r], then min/max by sel
template<int CTRL>
__device__ inline void cross_rev(float (&v)[32], float sel) {
    float t[32];
    #pragma unroll
    for (int r = 0; r < 32; r++) t[r] = dppmov<CTRL>(v[31 - r]);
    #pragma unroll
    for (int r = 0; r < 32; r++) v[r] = med3(v[r], t[r], sel);
}
// cross-lane same-index gather (xor cleaner)
template<int CTRL>
__device__ inline void cross_same(float (&v)[32], float sel) {
    float t[32];
    #pragma unroll
    for (int r = 0; r < 32; r++) t[r] = dppmov<CTRL>(v[r]);
    #pragma unroll
    for (int r = 0; r < 32; r++) v[r] = med3(v[r], t[r], sel);
}

// merges m=32,64,128 (after both 16-halves are sorted ascending)
__device__ inline void merge_hi(float (&v)[32], float M1, float M2) {
    // m=32: in-lane reflection + ascending cleaners
    reflect<0, 32, 32>(v);
    clean<0, 32, 8>(v); clean<0, 32, 4>(v); clean<0, 32, 2>(v); clean<0, 32, 1>(v);
    // m=64: reflect across lane^1 (reg-reversed), then in-lane cleaners
    cross_rev<QP_XOR1>(v, M1);
    clean<0, 32, 16>(v); clean<0, 32, 8>(v); clean<0, 32, 4>(v);
    clean<0, 32, 2>(v);  clean<0, 32, 1>(v);
    // m=128: reflect across lane^3 (reg-reversed), dist-32 cleaner across lane^1,
    // then in-lane cleaners
    cross_rev<QP_XOR3>(v, M2);
    cross_same<QP_XOR1>(v, M1);
    clean<0, 32, 16>(v); clean<0, 32, 8>(v); clean<0, 32, 4>(v);
    clean<0, 32, 2>(v);  clean<0, 32, 1>(v);
}

__global__ __launch_bounds__(256) void iqe_union_kernel(
    const float* __restrict__ x, const float* __restrict__ y,
    float* __restrict__ out, int B)
{
    const int tid = threadIdx.x;
    const int g   = tid & 3;                        // lane within 4-lane row group
    const int row = blockIdx.x * 64 + (tid >> 2);   // 64 rows per 256-thread block
    if (row >= B) return;

    const size_t rbase = (size_t)row * D;
    float a[32], b[32];
    // lo halves first, then hi halves: the hi loads' latency hides under the
    // lo-half mask+sort (compiler waits vmcnt(8) before touching lo regs).
    #pragma unroll
    for (int t = 0; t < 4; t++)
        *reinterpret_cast<float4*>(&a[4 * t]) = *reinterpret_cast<const float4*>(x + rbase + 16 * t + 4 * g);
    #pragma unroll
    for (int t = 0; t < 4; t++)
        *reinterpret_cast<float4*>(&b[4 * t]) = *reinterpret_cast<const float4*>(y + rbase + 16 * t + 4 * g);
    #pragma unroll
    for (int t = 4; t < 8; t++)
        *reinterpret_cast<float4*>(&a[4 * t]) = *reinterpret_cast<const float4*>(x + rbase + 16 * t + 4 * g);
    #pragma unroll
    for (int t = 4; t < 8; t++)
        *reinterpret_cast<float4*>(&b[4 * t]) = *reinterpret_cast<const float4*>(y + rbase + 16 * t + 4 * g);

    // per-lane +-INF selectors: lower lane of a block keeps min (-INF), upper max (+INF)
    const float S1 = (g & 1) ? 1.f : -1.f;
    const float S2 = (g & 2) ? 1.f : -1.f;
    const float M1 = S1 * INF;
    const float M2 = S2 * INF;

    // mask lo half (invalid intervals -> +INF in both arrays), sort 16-blocks
    #pragma unroll
    for (int r = 0; r < 16; r++) {
        const bool v = a[r] < b[r];
        a[r] = v ? a[r] : FLT_MAX;
        b[r] = v ? b[r] : FLT_MAX;
    }
    sort16<0>(a);  sort16<0>(b);

    // mask + sort hi half (hi loads have landed by now)
    #pragma unroll
    for (int r = 16; r < 32; r++) {
        const bool v = a[r] < b[r];
        a[r] = v ? a[r] : FLT_MAX;
        b[r] = v ? b[r] : FLT_MAX;
    }
    sort16<16>(a); sort16<16>(b);

    // merges m=32..128
    merge_hi(a, M1, M2);
    merge_hi(b, M1, M2);

    // ---- epilogue: sum max(0, b_e - max(a_e, b_{e-1})) ----
    float prev = dppmov<QP_SHR1>(b[31]);    // previous lane's last b
    if (g == 0) prev = -FLT_MAX;            // b_{-1} = -inf (row boundary)
    float c = 0.f;
    #pragma unroll
    for (int r = 0; r < 32; r++) {
        c += fmaxf(0.f, b[r] - fmaxf(a[r], prev));
        prev = b[r];
    }
    // reduce over the 4-lane group (quad_perm butterfly)
    c += dppmov<QP_XOR1>(c);
    c += dppmov<QP_XOR3>(c);   // xor3 completes the 4-lane sum just like xor2
    if (g == 0) out[row] = c;
}

extern "C" void kernel_launch(void* const* d_in, const int* in_sizes, int n_in,
                              void* d_out, int out_size, void* d_ws, size_t ws_size,
                              hipStream_t stream) {
    const float* x = (const float*)d_in[0];
    const float* y = (const float*)d_in[1];
    float* out = (float*)d_out;
    const int B = in_sizes[0] / D;            // 524288
    const int blocks = (B + 63) / 64;         // 64 rows per 256-thread block
    iqe_union_kernel<<<blocks, 256, 0, stream>>>(x, y, out, B);
}